// Round 7
// baseline (1388.637 us; speedup 1.0000x reference)
//
#include <hip/hip_runtime.h>
#include <hip/hip_bf16.h>

// 2-layer tanh RNN. B=256, T=1024, H=128, V=96. x int32; float tensors
// runtime-detected fp32 vs bf16.
// d_in: 0:x 1:emb 2:W_ih0 3:W_hh0 4:b_ih0 5:b_hh0 6:W_ih1 7:W_hh1 8:b_ih1
//       9:b_hh1 10:fc_W 11:fc_b
// d_out: out[B*T,96] ++ hidden[2,B,128]
//
// R7: layer-split producer/consumer pipeline on 32 CUs.
//  blocks 0-15  (producer): layer-0 recurrence; streams h0(t) (fp16, B-frag
//    layout, 4KB/group/step) into a workspace ring via agent-scope stores.
//  blocks 16-31 (consumer): layer-1 recurrence + FC; reads h0 frags straight
//    from the ring with agent-scope loads, prefetched 2 steps ahead; the
//    Wih1.h0 chain is computed one phase early (off the critical path).
//  Sync: per-group progress counters published every 8 steps (release/acquire
//  atomics). Producer is wait-free except ring back-pressure; no deadlock.
//  Correctness is XCD-placement-independent (agent scope everywhere).
// Fallback: R6 monolithic kernel when workspace < ring minimum.
//
// Workspace layout: [0,48K) embp f32 | [48K,48K+4K) flags | [52K..) h0 ring.

#define B_SZ 256
#define T_LEN 1024
#define HD 128
#define VC 96
#define OUT_MAIN (B_SZ * T_LEN * VC)
#define HID_OFF OUT_MAIN

#define NB 16              // batches per group
#define NBLK (B_SZ / NB)   // 16 groups
#define NT 512             // threads = 8 waves
#define EPH 132            // embp row stride (halves): mult of 4 -> b64 gather
#define HCH 136            // h chunk stride (halves): b128 frag reads

#define WS_FLAGS 49152
#define WS_CONSC 51200
#define WS_STREAM 53248

typedef _Float16 h8v __attribute__((ext_vector_type(8)));
typedef _Float16 h4v __attribute__((ext_vector_type(4)));
typedef _Float16 h2v __attribute__((ext_vector_type(2)));
typedef float f4v __attribute__((ext_vector_type(4)));

template <bool V> struct BoolT { static constexpr bool value = V; };
union UllH { unsigned long long u[2]; h8v h; };
union UllP { unsigned long long u; h4v h; };

#define MM(A, Bf, C) __builtin_amdgcn_mfma_f32_16x16x32_f16(A, Bf, C, 0, 0, 0)

// LDS-only barrier: drain LDS ops, never vmcnt (global traffic stays in flight).
#define BARRIER()                                          \
  do {                                                     \
    asm volatile("s_waitcnt lgkmcnt(0)" ::: "memory");     \
    __builtin_amdgcn_s_barrier();                          \
    asm volatile("" ::: "memory");                         \
  } while (0)

__device__ __forceinline__ float bf2f(__hip_bfloat16 v) { return __bfloat162float(v); }

__device__ __forceinline__ bool detect_f32(const void* emb) {
  const unsigned short* u = (const unsigned short*)emb;
  int hits = 0;
#pragma unroll
  for (int i = 0; i < 128; ++i) hits += (((u[i] >> 7) & 0xFF) >= 127);
  return hits > 2;
}

__device__ __forceinline__ float ldw(const void* p, int i, bool f32) {
  return f32 ? ((const float*)p)[i] : bf2f(((const __hip_bfloat16*)p)[i]);
}

// tanh(x) = 1 - 2/(e^{2x}+1), e^{2x} = 2^(x*2log2e). 3 VALU + 2 trans.
__device__ __forceinline__ float tanh_fast(float x) {
  const float e = exp2f(x * 2.885390082f);
  const float r = __builtin_amdgcn_rcpf(e + 1.0f);
  return fmaf(-2.0f, r, 1.0f);
}

// bf16 RNE round to bits (bounded values) — cold epilogues only.
__device__ __forceinline__ unsigned short f2bfbits(float x) {
  unsigned u = __float_as_uint(x);
  unsigned r = (u + 0x7fffu + ((u >> 16) & 1u)) >> 16;
  return (unsigned short)r;
}

// packed f32x2 -> bf16x2 (hot path, 1 instr)
__device__ __forceinline__ unsigned cvt_pk_bf16(float lo, float hi) {
  unsigned r;
  asm("v_cvt_pk_bf16_f32 %0, %1, %2" : "=v"(r) : "v"(lo), "v"(hi));
  return r;
}

__global__ __launch_bounds__(128) void embp_kernel(
    const void* __restrict__ emb, const void* __restrict__ Wih0,
    const void* __restrict__ bih0, const void* __restrict__ bhh0,
    float* __restrict__ embp) {
  const bool f32 = detect_f32(emb);
  __shared__ float ev[HD];
  const int v = blockIdx.x, r = threadIdx.x;
  ev[r] = ldw(emb, v * HD + r, f32);
  __syncthreads();
  float acc = ldw(bih0, r, f32) + ldw(bhh0, r, f32);
#pragma unroll 8
  for (int j = 0; j < HD; ++j) acc += ldw(Wih0, r * HD + j, f32) * ev[j];
  embp[v * HD + r] = acc;
}

// ===================== split pipeline kernel (32 blocks) =====================
// LDS h layout (both buffers): (batch m, hidden c) at (c>>3)*HCH + m*8 + (c&7).
// Stream layout per (group, slot): 2048 halves, chunk ch = c>>3 at ch*128+m*8+(c&7).
__global__ __launch_bounds__(NT, 2) void rnn_split(
    const int* __restrict__ x,
    const float* __restrict__ embp_g,
    const void* __restrict__ emb,
    const void* __restrict__ Whh0,
    const void* __restrict__ Wih1,
    const void* __restrict__ Whh1,
    const void* __restrict__ bih1,
    const void* __restrict__ bhh1,
    const void* __restrict__ fcW,
    const void* __restrict__ fcb_g,
    void* __restrict__ out,
    unsigned long long* __restrict__ streamU,
    unsigned* __restrict__ prodc,
    unsigned* __restrict__ consc,
    int Rsteps) {
  __shared__ __align__(16) _Float16 embp16[VC * EPH];            // 25344 B
  __shared__ __align__(16) _Float16 hb0[2][16 * HCH];            // 8704 B
  __shared__ __align__(16) _Float16 hb1[2][16 * HCH];            // 8704 B
  __shared__ __align__(16) unsigned char xb8[(T_LEN + 2) * NB];  // 16416 B

  const int tid = threadIdx.x;
  const int lane = tid & 63;
  const int w = tid >> 6;    // wave 0..7: owns 16 hidden/vocab rows
  const int lm = lane & 15;  // batch (B-frag col / D col)
  const int lg = lane >> 4;  // k-subchunk / D row group
  const bool f32 = detect_f32(emb);
  const int Rmask = Rsteps - 1;

  const int rdb = lg * HCH + lm * 8;
  const int wofs = (2 * w + (lg >> 1)) * HCH + lm * 8 + 4 * (lg & 1);

  float* outf = (float*)out;
  unsigned short* outu = (unsigned short*)out;

  if (blockIdx.x < NBLK) {
    // ============================ PRODUCER: layer 0 ============================
    const int g = blockIdx.x, g16 = g * 16;
    const int bbase = g * NB;
    const long gbaseU = (long)g * Rsteps * 512;  // ULL units
    const long psU = gbaseU + (2 * w + (lg >> 1)) * 32 + lm * 2 + (lg & 1);

    // stage token bytes xb8[t*16+m] (padded 2 steps)
    for (int i = tid; i < NB * T_LEN; i += NT) {
      const int m = i >> 10, t = i & (T_LEN - 1);
      xb8[t * 16 + m] = (unsigned char)x[(bbase + m) * T_LEN + t];
    }
    if (tid < 2 * NB) {
      const int t = T_LEN + (tid >> 4), m = tid & 15;
      xb8[t * 16 + m] = (unsigned char)x[(bbase + m) * T_LEN + (T_LEN - 1)];
    }
    // stage embp fp16
    {
      const float2* src = (const float2*)embp_g;
      for (int i = tid; i < VC * 64; i += NT) {
        const int v = i >> 6, j = i & 63;
        const float2 f = src[i];
        h2v p; p[0] = (_Float16)f.x; p[1] = (_Float16)f.y;
        ((h2v*)embp16)[v * (EPH / 2) + j] = p;
      }
    }
    for (int i = tid; i < 16 * HCH / 2; i += NT) ((unsigned*)hb0)[i] = 0u;
    if (tid < 16 * HCH / 2 * 2 - NT * ((16 * HCH / 2) / NT)) {}  // (loop covers all)
    for (int i = tid + 16 * HCH / 2; i < 16 * HCH; i += NT) ((unsigned*)hb0)[i] = 0u;

    // Whh0 A-frags: row 16w+lm, k = kt*32+lg*8+j
    h8v w0[4];
    {
      const int n = 16 * w + lm;
#pragma unroll
      for (int kt = 0; kt < 4; ++kt)
#pragma unroll
        for (int j = 0; j < 8; ++j)
          w0[kt][j] = (_Float16)ldw(Whh0, n * HD + (kt * 32 + lg * 8 + j), f32);
    }
    const int gofs = 16 * w + 4 * lg;
    __syncthreads();

    h4v epc;
    int xcur;
    const unsigned char* xbp = &xb8[2 * 16 + lm];
    {
      const int x0 = xb8[0 * 16 + lm];
      xcur = xb8[1 * 16 + lm];
      epc = *(const h4v*)&embp16[x0 * EPH + gofs];
    }
    unsigned ccL = 0;

#define PSTEP(TTX, Q, P)                                                       \
  do {                                                                         \
    if ((TTX) >= Rsteps) {                                                     \
      const int need_ = (TTX) - Rsteps + 16;                                   \
      while ((int)ccL * 8 < need_) {                                           \
        ccL = __hip_atomic_load(&consc[g16], __ATOMIC_ACQUIRE,                 \
                                __HIP_MEMORY_SCOPE_AGENT);                     \
        if ((int)ccL * 8 < need_) __builtin_amdgcn_s_sleep(16);                \
      }                                                                        \
    }                                                                          \
    h8v h0f[4];                                                                \
    _Pragma("unroll") for (int kt = 0; kt < 4; ++kt)                           \
        h0f[kt] = *(const h8v*)&hb0[Q][rdb + kt * 4 * HCH];                    \
    const int xnext_ = *xbp; xbp += 16;                                        \
    const h4v epn_ = *(const h4v*)&embp16[xcur * EPH + gofs];                  \
    f4v a0;                                                                    \
    a0[0] = (float)epc[0]; a0[1] = (float)epc[1];                              \
    a0[2] = (float)epc[2]; a0[3] = (float)epc[3];                              \
    a0 = MM(w0[0], h0f[0], a0); a0 = MM(w0[1], h0f[1], a0);                    \
    a0 = MM(w0[2], h0f[2], a0); a0 = MM(w0[3], h0f[3], a0);                    \
    h4v o;                                                                     \
    _Pragma("unroll") for (int r = 0; r < 4; ++r)                              \
        o[r] = (_Float16)tanh_fast(a0[r]);                                     \
    *(h4v*)&hb0[P][wofs] = o;                                                  \
    UllP up_; up_.h = o;                                                       \
    __hip_atomic_store(&streamU[psU + (long)((TTX) & Rmask) * 512], up_.u,     \
                       __ATOMIC_RELAXED, __HIP_MEMORY_SCOPE_AGENT);            \
    if (((TTX) & 7) == 7 && lane == 0)                                         \
      __hip_atomic_fetch_add(&prodc[g16], 1u, __ATOMIC_RELEASE,                \
                             __HIP_MEMORY_SCOPE_AGENT);                        \
    BARRIER();                                                                 \
    epc = epn_; xcur = xnext_;                                                 \
  } while (0)

#pragma unroll 1
    for (int tt = 0; tt < T_LEN; tt += 2) {
      PSTEP(tt, 1, 0);
      PSTEP(tt + 1, 0, 1);
    }
#undef PSTEP

    // hidden[0] epilogue: h0(T-1) in hb0[1]
    if (tid < 256) {
      const int m = tid >> 4, ch = tid & 15;
      const h8v v0 = *(const h8v*)&hb0[1][ch * HCH + m * 8];
      const long i0 = HID_OFF + (long)(bbase + m) * HD + ch * 8;
      if (f32) {
#pragma unroll
        for (int j = 0; j < 8; ++j) outf[i0 + j] = (float)v0[j];
      } else {
#pragma unroll
        for (int j = 0; j < 8; ++j) outu[i0 + j] = f2bfbits((float)v0[j]);
      }
    }
  } else {
    // ====================== CONSUMER: layer 1 + FC ======================
    const int g = blockIdx.x - NBLK, g16 = g * 16;
    const int bbase = g * NB;
    const long gbaseU = (long)g * Rsteps * 512;
    const int lofsU = lg * 32 + lm * 2;  // + kt*128

    for (int i = tid; i < 16 * HCH; i += NT) ((unsigned*)hb1)[i] = 0u;

    const bool fcact = (w < 6);
    h8v wi[4], wh[4], wf[4];
    {
      const int n = 16 * w + lm;
#pragma unroll
      for (int kt = 0; kt < 4; ++kt)
#pragma unroll
        for (int j = 0; j < 8; ++j) {
          const int k = kt * 32 + lg * 8 + j;
          wi[kt][j] = (_Float16)ldw(Wih1, n * HD + k, f32);
          wh[kt][j] = (_Float16)ldw(Whh1, n * HD + k, f32);
          wf[kt][j] = (_Float16)(fcact ? ldw(fcW, n * HD + k, f32) : 0.0f);
        }
    }
    f4v b1v, fcv;
#pragma unroll
    for (int r = 0; r < 4; ++r) {
      const int c = 16 * w + 4 * lg + r;
      b1v[r] = ldw(bih1, c, f32) + ldw(bhh1, c, f32);
      fcv[r] = fcact ? ldw(fcb_g, c, f32) : 0.0f;
    }
    __syncthreads();

    auto core = [&](auto f32tag) {
      constexpr bool F32 = decltype(f32tag)::value;
      constexpr long OSTRIDE = (long)VC * (F32 ? 4 : 2);
      char* po = (char*)out +
                 ((long)(bbase + lm) * T_LEN * VC + 16 * w + 4 * lg) * (F32 ? 4 : 2);

      // prologue: wait epoch 0; load h0(0)->t0, h0(1)->hgA; u_cur = b1+Wih1.h0(0)
      unsigned ppL = 0;
      while (ppL == 0) {
        ppL = __hip_atomic_load(&prodc[g16], __ATOMIC_ACQUIRE,
                                __HIP_MEMORY_SCOPE_AGENT);
        if (ppL == 0) __builtin_amdgcn_s_sleep(32);
      }
      h8v hgA[4], hgB[4];
      f4v u_cur = b1v, u_next;
      {
        h8v t0[4];
#pragma unroll
        for (int kt = 0; kt < 4; ++kt) {
          UllH uh;
          uh.u[0] = __hip_atomic_load(&streamU[gbaseU + lofsU + kt * 128],
                                      __ATOMIC_RELAXED, __HIP_MEMORY_SCOPE_AGENT);
          uh.u[1] = __hip_atomic_load(&streamU[gbaseU + lofsU + kt * 128 + 1],
                                      __ATOMIC_RELAXED, __HIP_MEMORY_SCOPE_AGENT);
          t0[kt] = uh.h;
          UllH uh2;
          uh2.u[0] = __hip_atomic_load(&streamU[gbaseU + 512 + lofsU + kt * 128],
                                       __ATOMIC_RELAXED, __HIP_MEMORY_SCOPE_AGENT);
          uh2.u[1] = __hip_atomic_load(&streamU[gbaseU + 512 + lofsU + kt * 128 + 1],
                                       __ATOMIC_RELAXED, __HIP_MEMORY_SCOPE_AGENT);
          hgA[kt] = uh2.h;
        }
#pragma unroll
        for (int kt = 0; kt < 4; ++kt) u_cur = MM(wi[kt], t0[kt], u_cur);
      }

#define CSTEP(TTX, Q, P, HGN, HGF, DO_H1, DO_OUT, DO_UN, DO_PF)                \
  do {                                                                         \
    h8v h1f[4];                                                                \
    _Pragma("unroll") for (int kt = 0; kt < 4; ++kt)                           \
        h1f[kt] = *(const h8v*)&hb1[Q][rdb + kt * 4 * HCH];                    \
    if (DO_PF) {                                                               \
      const int sPF_ = (TTX) + 2;                                              \
      const int need_ = sPF_ + 1;                                              \
      while ((int)ppL * 8 < need_) {                                           \
        ppL = __hip_atomic_load(&prodc[g16], __ATOMIC_ACQUIRE,                 \
                                __HIP_MEMORY_SCOPE_AGENT);                     \
        if ((int)ppL * 8 < need_) __builtin_amdgcn_s_sleep(16);                \
      }                                                                        \
      const long sbu_ = gbaseU + (long)(sPF_ & Rmask) * 512;                   \
      _Pragma("unroll") for (int kt = 0; kt < 4; ++kt) {                       \
        UllH uh_;                                                              \
        uh_.u[0] = __hip_atomic_load(&streamU[sbu_ + lofsU + kt * 128],        \
                                     __ATOMIC_RELAXED, __HIP_MEMORY_SCOPE_AGENT);\
        uh_.u[1] = __hip_atomic_load(&streamU[sbu_ + lofsU + kt * 128 + 1],    \
                                     __ATOMIC_RELAXED, __HIP_MEMORY_SCOPE_AGENT);\
        HGF[kt] = uh_.h;                                                       \
      }                                                                        \
    }                                                                          \
    f4v a1 = u_cur;                                                            \
    a1 = MM(wh[0], h1f[0], a1); a1 = MM(wh[1], h1f[1], a1);                    \
    a1 = MM(wh[2], h1f[2], a1); a1 = MM(wh[3], h1f[3], a1);                    \
    if (DO_UN) {                                                               \
      u_next = b1v;                                                            \
      u_next = MM(wi[0], HGN[0], u_next); u_next = MM(wi[1], HGN[1], u_next);  \
      u_next = MM(wi[2], HGN[2], u_next); u_next = MM(wi[3], HGN[3], u_next);  \
    }                                                                          \
    if (DO_OUT) {                                                              \
      f4v fo = fcv;                                                            \
      fo = MM(wf[0], h1f[0], fo); fo = MM(wf[1], h1f[1], fo);                  \
      fo = MM(wf[2], h1f[2], fo); fo = MM(wf[3], h1f[3], fo);                  \
      if (fcact) {                                                             \
        if constexpr (F32) {                                                   \
          *(f4v*)po = fo;                                                      \
        } else {                                                               \
          uint2 u_;                                                            \
          u_.x = cvt_pk_bf16(fo[0], fo[1]);                                    \
          u_.y = cvt_pk_bf16(fo[2], fo[3]);                                    \
          *(uint2*)po = u_;                                                    \
        }                                                                      \
        po += OSTRIDE;                                                         \
      }                                                                        \
    }                                                                          \
    if (DO_H1) {                                                               \
      h4v o_;                                                                  \
      _Pragma("unroll") for (int r = 0; r < 4; ++r)                            \
          o_[r] = (_Float16)tanh_fast(a1[r]);                                  \
      *(h4v*)&hb1[P][wofs] = o_;                                               \
    }                                                                          \
    if (((TTX) & 7) == 7 && lane == 0)                                         \
      __hip_atomic_fetch_add(&consc[g16], 1u, __ATOMIC_RELEASE,                \
                             __HIP_MEMORY_SCOPE_AGENT);                        \
    BARRIER();                                                                 \
    u_cur = u_next;                                                            \
  } while (0)

      CSTEP(0, 1, 0, hgA, hgB, true, false, true, true);  // h1(0)
      CSTEP(1, 0, 1, hgB, hgA, true, true, true, true);   // h1(1), out(0)
#pragma unroll 1
      for (int tt = 2; tt < T_LEN; tt += 2) {
        CSTEP(tt, 1, 0, hgA, hgB, true, true, true, (tt + 2 < T_LEN));
        CSTEP(tt + 1, 0, 1, hgB, hgA, true, true, (tt + 2 < T_LEN),
              (tt + 3 < T_LEN));
      }
      // tail: out(T-1) from h1(T-1) in hb1[1]
      {
        h8v h1f[4];
#pragma unroll
        for (int kt = 0; kt < 4; ++kt)
          h1f[kt] = *(const h8v*)&hb1[1][rdb + kt * 4 * HCH];
        f4v fo = fcv;
        fo = MM(wf[0], h1f[0], fo); fo = MM(wf[1], h1f[1], fo);
        fo = MM(wf[2], h1f[2], fo); fo = MM(wf[3], h1f[3], fo);
        if (fcact) {
          if constexpr (F32) {
            *(f4v*)po = fo;
          } else {
            uint2 u_;
            u_.x = cvt_pk_bf16(fo[0], fo[1]);
            u_.y = cvt_pk_bf16(fo[2], fo[3]);
            *(uint2*)po = u_;
          }
        }
      }
#undef CSTEP

      // hidden[1] epilogue: h1(T-1) in hb1[1]
      if (tid < 256) {
        const int m = tid >> 4, ch = tid & 15;
        const h8v v1 = *(const h8v*)&hb1[1][ch * HCH + m * 8];
        const long i1 = HID_OFF + (long)B_SZ * HD + (long)(bbase + m) * HD + ch * 8;
        if constexpr (F32) {
#pragma unroll
          for (int j = 0; j < 8; ++j) outf[i1 + j] = (float)v1[j];
        } else {
#pragma unroll
          for (int j = 0; j < 8; ++j) outu[i1 + j] = f2bfbits((float)v1[j]);
        }
      }
    };
    if (f32) core(BoolT<true>{});
    else core(BoolT<false>{});
  }
}

// ===================== monolithic fallback (R6, verified) =====================
template <bool USE_WS>
__global__ __launch_bounds__(NT, 2) void rnn_mono(
    const int* __restrict__ x, const float* __restrict__ embp_g,
    const void* __restrict__ emb, const void* __restrict__ Wih0,
    const void* __restrict__ bih0, const void* __restrict__ bhh0,
    const void* __restrict__ Whh0, const void* __restrict__ Wih1,
    const void* __restrict__ Whh1, const void* __restrict__ bih1,
    const void* __restrict__ bhh1, const void* __restrict__ fcW,
    const void* __restrict__ fcb_g, void* __restrict__ out) {
  __shared__ __align__(16) _Float16 embp16[VC * EPH];
  __shared__ __align__(16) _Float16 hb0[2][16 * HCH];
  __shared__ __align__(16) _Float16 hb1[2][16 * HCH];
  __shared__ __align__(16) unsigned char xb8[(T_LEN + 2) * NB];

  const int tid = threadIdx.x;
  const int lane = tid & 63;
  const int w = tid >> 6;
  const int lm = lane & 15;
  const int lg = lane >> 4;
  const bool f32 = detect_f32(emb);
  const int bbase = blockIdx.x * NB;

  for (int i = tid; i < NB * T_LEN; i += NT) {
    const int m = i >> 10, t = i & (T_LEN - 1);
    xb8[t * 16 + m] = (unsigned char)x[(bbase + m) * T_LEN + t];
  }
  if (tid < 2 * NB) {
    const int t = T_LEN + (tid >> 4), m = tid & 15;
    xb8[t * 16 + m] = (unsigned char)x[(bbase + m) * T_LEN + (T_LEN - 1)];
  }
  if constexpr (USE_WS) {
    const float2* src = (const float2*)embp_g;
    for (int i = tid; i < VC * 64; i += NT) {
      const int v = i >> 6, j = i & 63;
      const float2 f = src[i];
      h2v p; p[0] = (_Float16)f.x; p[1] = (_Float16)f.y;
      ((h2v*)embp16)[v * (EPH / 2) + j] = p;
    }
  } else {
    const int r = tid & 127, vg = tid >> 7;
    const float bsum = ldw(bih0, r, f32) + ldw(bhh0, r, f32);
    for (int vi = 0; vi < 24; ++vi) {
      const int v = vg * 24 + vi;
      float acc = bsum;
#pragma unroll 8
      for (int k = 0; k < HD; ++k)
        acc += ldw(Wih0, r * HD + k, f32) * ldw(emb, v * HD + k, f32);
      embp16[v * EPH + r] = (_Float16)acc;
    }
  }
  for (int i = tid; i < 16 * HCH; i += NT) {
    ((unsigned*)hb0)[i] = 0u;
    ((unsigned*)hb1)[i] = 0u;
  }
  const bool fcact = (w < 6);
  h8v w0[4], wi[4], wh[4], wf[4];
  {
    const int n = 16 * w + lm;
#pragma unroll
    for (int kt = 0; kt < 4; ++kt)
#pragma unroll
      for (int j = 0; j < 8; ++j) {
        const int k = kt * 32 + lg * 8 + j;
        w0[kt][j] = (_Float16)ldw(Whh0, n * HD + k, f32);
        wi[kt][j] = (_Float16)ldw(Wih1, n * HD + k, f32);
        wh[kt][j] = (_Float16)ldw(Whh1, n * HD + k, f32);
        wf[kt][j] = (_Float16)(fcact ? ldw(fcW, n * HD + k, f32) : 0.0f);
      }
  }
  f4v b1v, fcv;
#pragma unroll
  for (int r = 0; r < 4; ++r) {
    const int c = 16 * w + 4 * lg + r;
    b1v[r] = ldw(bih1, c, f32) + ldw(bhh1, c, f32);
    fcv[r] = fcact ? ldw(fcb_g, c, f32) : 0.0f;
  }
  const int rdb = lg * HCH + lm * 8;
  const int wofs = (2 * w + (lg >> 1)) * HCH + lm * 8 + 4 * (lg & 1);
  const int gofs = 16 * w + 4 * lg;
  __syncthreads();

  auto core = [&](auto f32tag) {
    constexpr bool F32 = decltype(f32tag)::value;
    h4v epc;
    int xcur;
    const unsigned char* xbp = &xb8[2 * 16 + lm];
    {
      const int x0 = xb8[0 * 16 + lm];
      xcur = xb8[1 * 16 + lm];
      epc = *(const h4v*)&embp16[x0 * EPH + gofs];
    }
    constexpr long OSTRIDE = (long)VC * (F32 ? 4 : 2);
    char* po = (char*)out +
               ((long)(bbase + lm) * T_LEN * VC + 16 * w + 4 * lg) * (F32 ? 4 : 2);

#define MSTEP(Q, P, DO_H0, DO_H1, DO_OUT)                                      \
  do {                                                                         \
    h8v h0f[4], h1f[4];                                                        \
    _Pragma("unroll") for (int kt = 0; kt < 4; ++kt) {                         \
      if (DO_H0 || DO_H1) h0f[kt] = *(const h8v*)&hb0[Q][rdb + kt * 4 * HCH];  \
      h1f[kt] = *(const h8v*)&hb1[Q][rdb + kt * 4 * HCH];                      \
    }                                                                          \
    int xnext_ = 0;                                                            \
    h4v epn_ = epc;                                                            \
    if (DO_H0) {                                                               \
      xnext_ = *xbp; xbp += 16;                                                \
      epn_ = *(const h4v*)&embp16[xcur * EPH + gofs];                          \
    }                                                                          \
    f4v a0, a1, a1c, a2;                                                       \
    if (DO_H0) {                                                               \
      a0[0] = (float)epc[0]; a0[1] = (float)epc[1];                            \
      a0[2] = (float)epc[2]; a0[3] = (float)epc[3];                            \
    }                                                                          \
    if (DO_H1) { a1 = b1v; a1c[0] = 0.f; a1c[1] = 0.f; a1c[2] = 0.f;           \
                 a1c[3] = 0.f; }                                               \
    if (DO_OUT) a2 = fcv;                                                      \
    _Pragma("unroll") for (int kt = 0; kt < 4; ++kt) {                         \
      if (DO_H0) a0 = MM(w0[kt], h0f[kt], a0);                                 \
      if (DO_H1) a1 = MM(wi[kt], h0f[kt], a1);                                 \
      if (DO_H1) a1c = MM(wh[kt], h1f[kt], a1c);                               \
      if (DO_OUT) a2 = MM(wf[kt], h1f[kt], a2);                                \
    }                                                                          \
    if (DO_H0) {                                                               \
      h4v o;                                                                   \
      _Pragma("unroll") for (int r = 0; r < 4; ++r)                            \
          o[r] = (_Float16)tanh_fast(a0[r]);                                   \
      *(h4v*)&hb0[P][wofs] = o;                                                \
    }                                                                          \
    if (DO_H1) {                                                               \
      const f4v s1 = a1 + a1c;                                                 \
      h4v o;                                                                   \
      _Pragma("unroll") for (int r = 0; r < 4; ++r)                            \
          o[r] = (_Float16)tanh_fast(s1[r]);                                   \
      *(h4v*)&hb1[P][wofs] = o;                                                \
    }                                                                          \
    if (DO_OUT && fcact) {                                                     \
      if constexpr (F32) {                                                     \
        *(f4v*)po = a2;                                                        \
      } else {                                                                 \
        uint2 u;                                                               \
        u.x = cvt_pk_bf16(a2[0], a2[1]);                                       \
        u.y = cvt_pk_bf16(a2[2], a2[3]);                                       \
        *(uint2*)po = u;                                                       \
      }                                                                        \
      po += OSTRIDE;                                                           \
    }                                                                          \
    BARRIER();                                                                 \
    if (DO_H0) { epc = epn_; xcur = xnext_; }                                  \
  } while (0)

    MSTEP(1, 0, true, false, false);
    MSTEP(0, 1, true, true, false);
#pragma unroll 1
    for (int tt = 2; tt < T_LEN; tt += 2) {
      MSTEP(1, 0, true, true, true);
      MSTEP(0, 1, true, true, true);
    }
    MSTEP(1, 0, false, true, true);
    MSTEP(0, 1, false, false, true);
#undef MSTEP

    float* outf = (float*)out;
    unsigned short* outu = (unsigned short*)out;
    if (tid < 256) {
      const int m = tid >> 4, ch = tid & 15;
      const h8v v0 = *(const h8v*)&hb0[1][ch * HCH + m * 8];
      const h8v v1 = *(const h8v*)&hb1[0][ch * HCH + m * 8];
      const long i0 = HID_OFF + (long)(bbase + m) * HD + ch * 8;
      const long i1 = i0 + (long)B_SZ * HD;
      if constexpr (F32) {
#pragma unroll
        for (int j = 0; j < 8; ++j) {
          outf[i0 + j] = (float)v0[j];
          outf[i1 + j] = (float)v1[j];
        }
      } else {
#pragma unroll
        for (int j = 0; j < 8; ++j) {
          outu[i0 + j] = f2bfbits((float)v0[j]);
          outu[i1 + j] = f2bfbits((float)v1[j]);
        }
      }
    }
  };
  if (f32) core(BoolT<true>{});
  else core(BoolT<false>{});
}

extern "C" void kernel_launch(void* const* d_in, const int* in_sizes, int n_in,
                              void* d_out, int out_size, void* d_ws, size_t ws_size,
                              hipStream_t stream) {
  const int* x = (const int*)d_in[0];
  const void* emb = d_in[1];
  const void* Wih0 = d_in[2];
  const void* Whh0 = d_in[3];
  const void* bih0 = d_in[4];
  const void* bhh0 = d_in[5];
  const void* Wih1 = d_in[6];
  const void* Whh1 = d_in[7];
  const void* bih1 = d_in[8];
  const void* bhh1 = d_in[9];
  const void* fcW = d_in[10];
  const void* fcb = d_in[11];

  // split path needs: embp (48K) + flags (4K) + ring (>= 64 slots x 16 x 4KB)
  long Rsteps = 0;
  if (d_ws != nullptr && ws_size > (size_t)WS_STREAM + 64ul * 65536ul) {
    size_t slots = (ws_size - WS_STREAM) / 65536ul;  // 16 groups x 4KB per slot
    if (slots > 1024) slots = 1024;
    long r = 64;
    while (r * 2 <= (long)slots) r <<= 1;
    Rsteps = r;
  }

  if (Rsteps >= 64) {
    char* wsb = (char*)d_ws;
    float* embp = (float*)wsb;
    unsigned* prodc = (unsigned*)(wsb + WS_FLAGS);
    unsigned* consc = (unsigned*)(wsb + WS_CONSC);
    unsigned long long* streamU = (unsigned long long*)(wsb + WS_STREAM);
    hipMemsetAsync(wsb + WS_FLAGS, 0, 4096, stream);
    embp_kernel<<<VC, HD, 0, stream>>>(emb, Wih0, bih0, bhh0, embp);
    rnn_split<<<2 * NBLK, NT, 0, stream>>>(x, embp, emb, Whh0, Wih1, Whh1,
                                           bih1, bhh1, fcW, fcb, d_out,
                                           streamU, prodc, consc, (int)Rsteps);
  } else if (d_ws != nullptr && ws_size >= (size_t)VC * HD * sizeof(float)) {
    float* embp = (float*)d_ws;
    embp_kernel<<<VC, HD, 0, stream>>>(emb, Wih0, bih0, bhh0, embp);
    rnn_mono<true><<<NBLK, NT, 0, stream>>>(x, embp, emb, Wih0, bih0, bhh0,
                                            Whh0, Wih1, Whh1, bih1, bhh1,
                                            fcW, fcb, d_out);
  } else {
    rnn_mono<false><<<NBLK, NT, 0, stream>>>(x, nullptr, emb, Wih0, bih0, bhh0,
                                             Whh0, Wih1, Whh1, bih1, bhh1,
                                             fcW, fcb, d_out);
  }
}